// Round 4
// baseline (1454.556 us; speedup 1.0000x reference)
//
#include <hip/hip_runtime.h>
#include <hip/hip_bf16.h>

typedef __bf16 bf16x8 __attribute__((ext_vector_type(8)));
typedef float f32x4 __attribute__((ext_vector_type(4)));
typedef unsigned short ushort_t;

#define LOG2E      1.4426950408889634f
#define SELU_SCALE 1.0507009873554805f
#define SELU_ALPHA 1.6732632423543772f

__device__ __forceinline__ float fexp2(float x){ return __builtin_amdgcn_exp2f(x); }
__device__ __forceinline__ float frcp (float x){ return __builtin_amdgcn_rcpf(x); }
__device__ __forceinline__ float tanh_fast(float x){
  return 1.0f - 2.0f * frcp(fexp2(x * (2.0f * LOG2E)) + 1.0f);
}
__device__ __forceinline__ float sigmoid_fast(float x){
  return frcp(1.0f + fexp2(-LOG2E * x));
}
__device__ __forceinline__ float selu_fast(float x){
  float e = SELU_ALPHA * (fexp2(LOG2E * x) - 1.0f);
  return SELU_SCALE * (x > 0.0f ? x : e);
}
__device__ __forceinline__ unsigned short f2bf(float f){
  unsigned u = __builtin_bit_cast(unsigned, f);
  u += 0x7fffu + ((u >> 16) & 1u);          // RNE
  return (unsigned short)(u >> 16);
}
__device__ __forceinline__ unsigned pk2(float a, float b){
#if __has_builtin(__builtin_amdgcn_cvt_pk_bf16_f32)
  typedef __bf16 bf2 __attribute__((ext_vector_type(2)));
  union { bf2 v; unsigned u; } c;
  c.v = __builtin_amdgcn_cvt_pk_bf16_f32(a, b);
  return c.u;
#else
  unsigned ua = __builtin_bit_cast(unsigned, a);
  ua += 0x7fffu + ((ua >> 16) & 1u);
  unsigned ub = __builtin_bit_cast(unsigned, b);
  ub += 0x7fffu + ((ub >> 16) & 1u);
  return (ua >> 16) | (ub & 0xffff0000u);
#endif
}
__device__ __forceinline__ bf16x8 pack8(float4 a, float4 b){
  union { bf16x8 v; unsigned u[4]; } c;
  c.u[0] = pk2(a.x, a.y); c.u[1] = pk2(a.z, a.w);
  c.u[2] = pk2(b.x, b.y); c.u[3] = pk2(b.z, b.w);
  return c.v;
}
__device__ __forceinline__ int imin(int a, int b){ return a < b ? a : b; }

// largest g in [lo,hi] with offs[g] <= n
__device__ __forceinline__ int find_graph(const int* __restrict__ offs, int lo, int hi, int n){
  while (lo < hi){
    int mid = (lo + hi + 1) >> 1;
    if (offs[mid] <= n) lo = mid; else hi = mid - 1;
  }
  return lo;
}

// Weight prep. Fragment-native layouts so every fused-kernel weight load is a
// lane-contiguous 16B load:
//   w1A[((mt*2+kb)*64 + lane)*8 + i] = W1fold[k = kb*32 + (lane>>4)*8 + i]
//                                           [feat = F(mt, lane&15)]
//   F(mt,row) = 32*(mt>>1) + 8*(row>>2) + 4*(mt&1) + (row&3)
//   (row-permutation makes the L1 C-tile pair (2u,2u+1) assemble into a
//    NATURAL-order 16x16x32 B-fragment for layer 2 -- no LDS transpose)
//   w2A[((nt*4+u)*64 + lane)*8 + i] = W2T[out = nt*16 + (lane&15)]
//                                        [feat = u*32 + (lane>>4)*8 + i]
// blocks 0..191: weights; block 192: prefix scan; blocks 193..: zero pooled
__global__ __launch_bounds__(256) void prep_kernel(
    const float* __restrict__ i1w, const float* __restrict__ j1w,
    const float* __restrict__ i2w, const float* __restrict__ j2w,
    ushort_t* __restrict__ wi1A, ushort_t* __restrict__ wj1A,
    ushort_t* __restrict__ wi2A, ushort_t* __restrict__ wj2A,
    const int* __restrict__ n_node, int* __restrict__ offs,
    float* __restrict__ pooled, int B){
  if (blockIdx.x >= 193){
    int id = (blockIdx.x - 193) * 256 + threadIdx.x;
    if (id < B * 128) pooled[id] = 0.0f;
    return;
  }
  if (blockIdx.x == 192){
    __shared__ int part[256];
    const int t = threadIdx.x;
    const int chunk = (B + 255) / 256;
    int s = 0;
    for (int i = 0; i < chunk; ++i){ int idx = t * chunk + i; if (idx < B) s += n_node[idx]; }
    part[t] = s;
    __syncthreads();
    if (t == 0){
      int run = 0;
      for (int i = 0; i < 256; ++i){ int v = part[i]; part[i] = run; run += v; }
      offs[B] = run;
    }
    __syncthreads();
    int run = part[t];
    for (int i = 0; i < chunk; ++i){
      int idx = t * chunk + i;
      if (idx < B){ offs[idx] = run; run += n_node[idx]; }
    }
    return;
  }
  int id = blockIdx.x * 256 + threadIdx.x;
  if (id < 16384){                              // w1A (i and j)
    int m = id & 8191;
    int i = m & 7, lane = (m >> 3) & 63, kbmt = m >> 9;
    int kb = kbmt & 1, mt = kbmt >> 1;
    int row = lane & 15;
    int feat = 32 * (mt >> 1) + 8 * (row >> 2) + 4 * (mt & 1) + (row & 3);
    int k = kb * 32 + ((lane >> 4) & 3) * 8 + i;
    const float* w = (id < 8192) ? i1w : j1w;
    float v = w[k * 128 + feat];
    if (k < 2) v += w[(64 + k) * 128 + feat];   // fold hx dup-columns
    ((id < 8192) ? wi1A : wj1A)[m] = f2bf(v);
  } else if (id < 49152){                       // w2A (i and j)
    int m = (id - 16384) & 16383;
    int i = m & 7, lane = (m >> 3) & 63, unt = m >> 9;
    int u = unt & 3, nt = unt >> 2;
    int out  = nt * 16 + (lane & 15);
    int feat = u * 32 + ((lane >> 4) & 3) * 8 + i;
    const float* w = (id < 32768) ? i2w : j2w;
    ((id < 32768) ? wi2A : wj2A)[m] = f2bf(w[feat * 128 + out]);
  }
}

// Persistent weight-stationary kernel. 512-thread block = 8 waves.
// Block loads w2A (both branches, 64 KB) into LDS ONCE, syncs once, then each
// wave grid-strides over 32-node tiles with the zero-transpose register
// pipeline (L1: C-layout + in-register activations -> natural-order L2
// B-fragments; L2: A = w2A from LDS). w1A (32 KB total) stays global: it is
// L1-resident and shared by all 16 waves/CU. Per-tile L2 weight stream is
// eliminated (was 3 GB of L2 traffic; now 33 MB one-time).
// LDS 64 KB -> 2 blocks/CU -> 16 waves/CU; VGPR capped 128 by (512,4).
__global__ __launch_bounds__(512, 4) void fused_node_kernel(
    const float* __restrict__ nodes, const float* __restrict__ node_mask,
    const int* __restrict__ offs,
    const ushort_t* __restrict__ wi1A, const ushort_t* __restrict__ wj1A,
    const ushort_t* __restrict__ w2A,   // wi2A || wj2A, contiguous 64 KB
    const float* __restrict__ i1b, const float* __restrict__ i2b,
    const float* __restrict__ j1b, const float* __restrict__ j2b,
    float* __restrict__ pooled, int N, int B){

  __shared__ __align__(16) ushort_t W2s[32768];   // 64 KB: i at 0, j at 16384

  const int tid  = threadIdx.x;
  const int lane = tid & 63;
  const int lm   = lane & 15;
  const int quad = (lane >> 4) & 3;
  const int wv   = tid >> 6;

  // ---- one-time cooperative LDS fill (4096 x 16B) ----
  #pragma unroll
  for (int c = 0; c < 8; ++c)
    ((uint4*)W2s)[tid + c * 512] = ((const uint4*)w2A)[tid + c * 512];
  __syncthreads();

  const f32x4 z4 = {0.f, 0.f, 0.f, 0.f};
  const int tile_stride = gridDim.x * 8;

  for (int tile = blockIdx.x * 8 + wv; tile * 32 < N; tile += tile_stride){
    const int base = tile * 32;

    // ---- graph range for this 32-node tile ----
    const int wg0 = __builtin_amdgcn_readfirstlane(find_graph(offs, 0, B - 1, base));
    const int wg1 = __builtin_amdgcn_readfirstlane(find_graph(offs, 0, B - 1, imin(base + 31, N - 1)));
    const bool caseA = (wg0 == wg1);

    // ---- per-lane node mask (node = base + s*16 + lm) ----
    float mkn[2];
    #pragma unroll
    for (int s = 0; s < 2; ++s){
      int node = base + s * 16 + lm;
      mkn[s] = (node < N) ? node_mask[node] : 0.0f;
    }

    // ---- split-tile per-lane graph ids (rare) ----
    int gfs[2], gls[2], grn[2];
    if (!caseA){
      #pragma unroll
      for (int s = 0; s < 2; ++s){
        gfs[s] = __builtin_amdgcn_readfirstlane(
                   find_graph(offs, wg0, wg1, imin(base + s * 16, N - 1)));
        gls[s] = __builtin_amdgcn_readfirstlane(
                   find_graph(offs, wg0, wg1, imin(base + s * 16 + 15, N - 1)));
        grn[s] = find_graph(offs, gfs[s], gls[s], imin(base + s * 16 + lm, N - 1));
      }
    }

    // ---- node B-fragments: 2 sets x 2 k-tiles ----
    bf16x8 nb[2][2];
    #pragma unroll
    for (int s = 0; s < 2; ++s){
      const int node = imin(base + s * 16 + lm, N - 1);
      const float* p = nodes + (size_t)node * 64;
      #pragma unroll
      for (int kb = 0; kb < 2; ++kb){
        float4 q0 = *(const float4*)(p + kb * 32 + quad * 8);
        float4 q1 = *(const float4*)(p + kb * 32 + quad * 8 + 4);
        nb[s][kb] = pack8(q0, q1);
      }
    }

    bf16x8 HB[2][2][4];   // [branch][set][u] L2 B-fragments, 64 VGPR

    // ---- layer 1: C-layout out, activations in-register, assemble HB ----
    #pragma unroll
    for (int br = 0; br < 2; ++br){
      const ushort_t* w1 = br ? wj1A : wi1A;
      const float*    b1 = br ? j1b  : i1b;
      #pragma unroll
      for (int u = 0; u < 4; ++u){
        unsigned t0[2], t1[2];
        #pragma unroll
        for (int half = 0; half < 2; ++half){
          const int mt = u * 2 + half;
          bf16x8 a0 = *(const bf16x8*)(w1 + ((size_t)(mt * 2 + 0) * 64 + lane) * 8);
          bf16x8 a1 = *(const bf16x8*)(w1 + ((size_t)(mt * 2 + 1) * 64 + lane) * 8);
          float4 bv = *(const float4*)(b1 + u * 32 + quad * 8 + half * 4);
          #pragma unroll
          for (int s = 0; s < 2; ++s){
            f32x4 acc = z4;
            acc = __builtin_amdgcn_mfma_f32_16x16x32_bf16(a0, nb[s][0], acc, 0, 0, 0);
            acc = __builtin_amdgcn_mfma_f32_16x16x32_bf16(a1, nb[s][1], acc, 0, 0, 0);
            float v0 = acc[0] + bv.x, v1 = acc[1] + bv.y;
            float v2 = acc[2] + bv.z, v3 = acc[3] + bv.w;
            if (br == 0){
              v0 = tanh_fast(v0); v1 = tanh_fast(v1); v2 = tanh_fast(v2); v3 = tanh_fast(v3);
            } else {
              v0 = selu_fast(v0); v1 = selu_fast(v1); v2 = selu_fast(v2); v3 = selu_fast(v3);
            }
            unsigned p0 = pk2(v0, v1), p1 = pk2(v2, v3);
            if (half == 0){ t0[s] = p0; t1[s] = p1; }
            else {
              union { bf16x8 v; unsigned w[4]; } c;
              c.w[0] = t0[s]; c.w[1] = t1[s]; c.w[2] = p0; c.w[3] = p1;
              HB[br][s][u] = c.v;
            }
          }
        }
      }
    }

    // ---- layer 2 + gate + mask + pooled reduction (w2 from LDS) ----
    #pragma unroll
    for (int nt = 0; nt < 8; ++nt){
      float4 c2i = *(const float4*)(i2b + nt * 16 + quad * 4);
      float4 c2j = *(const float4*)(j2b + nt * 16 + quad * 4);
      f32x4 ai[2] = {z4, z4}, aj[2] = {z4, z4};
      #pragma unroll
      for (int u = 0; u < 4; ++u){
        bf16x8 wai = *(const bf16x8*)(W2s + ((size_t)(nt * 4 + u) * 64 + lane) * 8);
        bf16x8 waj = *(const bf16x8*)(W2s + 16384 + ((size_t)(nt * 4 + u) * 64 + lane) * 8);
        #pragma unroll
        for (int s = 0; s < 2; ++s){
          ai[s] = __builtin_amdgcn_mfma_f32_16x16x32_bf16(wai, HB[0][s][u], ai[s], 0, 0, 0);
          aj[s] = __builtin_amdgcn_mfma_f32_16x16x32_bf16(waj, HB[1][s][u], aj[s], 0, 0, 0);
        }
      }
      const float cbi[4] = {c2i.x, c2i.y, c2i.z, c2i.w};
      const float cbj[4] = {c2j.x, c2j.y, c2j.z, c2j.w};
      if (caseA){
        float accr[4] = {0.f, 0.f, 0.f, 0.f};
        #pragma unroll
        for (int s = 0; s < 2; ++s)
          #pragma unroll
          for (int r = 0; r < 4; ++r){
            float g = sigmoid_fast(ai[s][r] + cbi[r]);
            accr[r] += g * (aj[s][r] + cbj[r]) * mkn[s];
          }
        #pragma unroll
        for (int r = 0; r < 4; ++r){
          accr[r] += __shfl_xor(accr[r], 1);
          accr[r] += __shfl_xor(accr[r], 2);
          accr[r] += __shfl_xor(accr[r], 4);
          accr[r] += __shfl_xor(accr[r], 8);
        }
        if (lm == 0){
          #pragma unroll
          for (int r = 0; r < 4; ++r)
            atomicAdd(&pooled[wg0 * 128 + nt * 16 + quad * 4 + r], accr[r]);
        }
      } else {
        #pragma unroll
        for (int s = 0; s < 2; ++s){
          float vals[4];
          #pragma unroll
          for (int r = 0; r < 4; ++r){
            float g = sigmoid_fast(ai[s][r] + cbi[r]);
            vals[r] = g * (aj[s][r] + cbj[r]) * mkn[s];
          }
          for (int g = gfs[s]; g <= gls[s]; ++g){
            float tt[4];
            #pragma unroll
            for (int r = 0; r < 4; ++r) tt[r] = (grn[s] == g) ? vals[r] : 0.0f;
            #pragma unroll
            for (int r = 0; r < 4; ++r){
              tt[r] += __shfl_xor(tt[r], 1);
              tt[r] += __shfl_xor(tt[r], 2);
              tt[r] += __shfl_xor(tt[r], 4);
              tt[r] += __shfl_xor(tt[r], 8);
            }
            if (lm == 0){
              #pragma unroll
              for (int r = 0; r < 4; ++r)
                atomicAdd(&pooled[g * 128 + nt * 16 + quad * 4 + r], tt[r]);
            }
          }
        }
      }
    }
  }
}

// head: out[g] = selu(pooled[g] @ h1_w + h1_b) @ h2_w + h2_b   (fp32)
__global__ __launch_bounds__(128) void head_kernel(
    const float* __restrict__ pooled, const float* __restrict__ h1w,
    const float* __restrict__ h1b, const float* __restrict__ h2w,
    const float* __restrict__ h2b, float* __restrict__ out){
  __shared__ float pg[128];
  __shared__ float red[64];
  const int g = blockIdx.x, t = threadIdx.x;
  pg[t] = pooled[g * 128 + t];
  __syncthreads();
  float acc = h1b[t];
  #pragma unroll 8
  for (int k = 0; k < 128; ++k) acc += pg[k] * h1w[k * 128 + t];
  float s = selu_fast(acc) * h2w[t];
  if (t >= 64) red[t - 64] = s;
  __syncthreads();
  if (t < 64){
    float v = s + red[t];
    #pragma unroll
    for (int o = 32; o > 0; o >>= 1) v += __shfl_down(v, o);
    if (t == 0) out[g] = v + h2b[0];
  }
}

extern "C" void kernel_launch(void* const* d_in, const int* in_sizes, int n_in,
                              void* d_out, int out_size, void* d_ws, size_t ws_size,
                              hipStream_t stream){
  const float* nodes     = (const float*)d_in[0];
  const float* node_mask = (const float*)d_in[1];
  const int*   n_node    = (const int*)  d_in[2];
  const float* i1w = (const float*)d_in[3];
  const float* i1b = (const float*)d_in[4];
  const float* i2w = (const float*)d_in[5];
  const float* i2b = (const float*)d_in[6];
  const float* j1w = (const float*)d_in[7];
  const float* j1b = (const float*)d_in[8];
  const float* j2w = (const float*)d_in[9];
  const float* j2b = (const float*)d_in[10];
  const float* h1w = (const float*)d_in[11];
  const float* h1b = (const float*)d_in[12];
  const float* h2w = (const float*)d_in[13];
  const float* h2b = (const float*)d_in[14];
  float* out = (float*)d_out;

  const int N = in_sizes[0] / 64;
  const int B = in_sizes[2];

  char* ws = (char*)d_ws;
  float* pooled = (float*)ws;                                    // B*128 f32
  size_t off = (size_t)B * 128 * 4;
  int* offs = (int*)(ws + off);                                  // B+1 ints
  off += (((size_t)(B + 1) * 4 + 255) & ~(size_t)255);
  ushort_t* wi1A = (ushort_t*)(ws + off);                        // 8192
  ushort_t* wj1A = wi1A + 8192;                                  // 8192
  ushort_t* wi2A = wj1A + 8192;                                  // 16384
  ushort_t* wj2A = wi2A + 16384;                                 // 16384 (contiguous with wi2A)

  int zblk = (B * 128 + 255) / 256;
  prep_kernel<<<193 + zblk, 256, 0, stream>>>(i1w, j1w, i2w, j2w, wi1A, wj1A, wi2A, wj2A,
                                              n_node, offs, pooled, B);

  int nblk = (N + 255) / 256; if (nblk > 512) nblk = 512;
  fused_node_kernel<<<nblk, 512, 0, stream>>>(nodes, node_mask, offs,
                                              wi1A, wj1A, wi2A,
                                              i1b, i2b, j1b, j2b, pooled, N, B);
  head_kernel<<<B, 128, 0, stream>>>(pooled, h1w, h1b, h2w, h2b, out);
}

// Round 5
// 560.265 us; speedup vs baseline: 2.5962x; 2.5962x over previous
//
#include <hip/hip_runtime.h>
#include <hip/hip_bf16.h>

typedef __bf16 bf16x8 __attribute__((ext_vector_type(8)));
typedef float f32x4 __attribute__((ext_vector_type(4)));
typedef unsigned short ushort_t;

#define LOG2E      1.4426950408889634f
#define SELU_SCALE 1.0507009873554805f
#define SELU_ALPHA 1.6732632423543772f

__device__ __forceinline__ float fexp2(float x){ return __builtin_amdgcn_exp2f(x); }
__device__ __forceinline__ float frcp (float x){ return __builtin_amdgcn_rcpf(x); }
__device__ __forceinline__ float tanh_fast(float x){
  return 1.0f - 2.0f * frcp(fexp2(x * (2.0f * LOG2E)) + 1.0f);
}
__device__ __forceinline__ float sigmoid_fast(float x){
  return frcp(1.0f + fexp2(-LOG2E * x));
}
__device__ __forceinline__ float selu_fast(float x){
  float e = SELU_ALPHA * (fexp2(LOG2E * x) - 1.0f);
  return SELU_SCALE * (x > 0.0f ? x : e);
}
__device__ __forceinline__ unsigned short f2bf(float f){
  unsigned u = __builtin_bit_cast(unsigned, f);
  u += 0x7fffu + ((u >> 16) & 1u);          // RNE
  return (unsigned short)(u >> 16);
}
__device__ __forceinline__ unsigned pk2(float a, float b){
#if __has_builtin(__builtin_amdgcn_cvt_pk_bf16_f32)
  typedef __bf16 bf2 __attribute__((ext_vector_type(2)));
  union { bf2 v; unsigned u; } c;
  c.v = __builtin_amdgcn_cvt_pk_bf16_f32(a, b);
  return c.u;
#else
  unsigned ua = __builtin_bit_cast(unsigned, a);
  ua += 0x7fffu + ((ua >> 16) & 1u);
  unsigned ub = __builtin_bit_cast(unsigned, b);
  ub += 0x7fffu + ((ub >> 16) & 1u);
  return (ua >> 16) | (ub & 0xffff0000u);
#endif
}
__device__ __forceinline__ bf16x8 pack8(float4 a, float4 b){
  union { bf16x8 v; unsigned u[4]; } c;
  c.u[0] = pk2(a.x, a.y); c.u[1] = pk2(a.z, a.w);
  c.u[2] = pk2(b.x, b.y); c.u[3] = pk2(b.z, b.w);
  return c.v;
}
__device__ __forceinline__ int imin(int a, int b){ return a < b ? a : b; }
__device__ __forceinline__ int imax(int a, int b){ return a > b ? a : b; }

// largest g in [lo,hi] with offs[g] <= n  (binary; used for narrow split ranges)
__device__ __forceinline__ int find_graph(const int* __restrict__ offs, int lo, int hi, int n){
  while (lo < hi){
    int mid = (lo + hi + 1) >> 1;
    if (offs[mid] <= n) lo = mid; else hi = mid - 1;
  }
  return lo;
}

// seeded + gallop: graphs are near-uniform (~N/B nodes), so the estimate is
// off by <=1-2; ~2-3 dependent loads instead of 11 binary-search probes.
__device__ __forceinline__ int find_graph_seeded(const int* __restrict__ offs,
                                                 int B, int n, int N){
  int g = (int)(((long long)n * B) / N);
  g = imin(imax(g, 0), B - 1);
  while (g < B - 1 && offs[g + 1] <= n) ++g;
  while (g > 0 && offs[g] > n) --g;
  return g;
}

// Weight prep. Fragment-native layouts so every fused-kernel weight load is a
// lane-contiguous 16B load:
//   w1A[((mt*2+kb)*64 + lane)*8 + i] = W1fold[k = kb*32 + (lane>>4)*8 + i]
//                                           [feat = F(mt, lane&15)]
//   F(mt,row) = 32*(mt>>1) + 8*(row>>2) + 4*(mt&1) + (row&3)
//   (row-permutation makes the L1 C-tile pair (2u,2u+1) assemble into a
//    NATURAL-order 16x16x32 B-fragment for layer 2 -- no LDS transpose)
//   w2A[((nt*4+u)*64 + lane)*8 + i] = W2T[out = nt*16 + (lane&15)]
//                                        [feat = u*32 + (lane>>4)*8 + i]
// blocks 0..191: weights; block 192: prefix scan; blocks 193..: zero pooled
__global__ __launch_bounds__(256) void prep_kernel(
    const float* __restrict__ i1w, const float* __restrict__ j1w,
    const float* __restrict__ i2w, const float* __restrict__ j2w,
    ushort_t* __restrict__ wi1A, ushort_t* __restrict__ wj1A,
    ushort_t* __restrict__ wi2A, ushort_t* __restrict__ wj2A,
    const int* __restrict__ n_node, int* __restrict__ offs,
    float* __restrict__ pooled, int B){
  if (blockIdx.x >= 193){
    int id = (blockIdx.x - 193) * 256 + threadIdx.x;
    if (id < B * 128) pooled[id] = 0.0f;
    return;
  }
  if (blockIdx.x == 192){
    __shared__ int part[256];
    const int t = threadIdx.x;
    const int chunk = (B + 255) / 256;
    int s = 0;
    for (int i = 0; i < chunk; ++i){ int idx = t * chunk + i; if (idx < B) s += n_node[idx]; }
    part[t] = s;
    __syncthreads();
    if (t == 0){
      int run = 0;
      for (int i = 0; i < 256; ++i){ int v = part[i]; part[i] = run; run += v; }
      offs[B] = run;
    }
    __syncthreads();
    int run = part[t];
    for (int i = 0; i < chunk; ++i){
      int idx = t * chunk + i;
      if (idx < B){ offs[idx] = run; run += n_node[idx]; }
    }
    return;
  }
  int id = blockIdx.x * 256 + threadIdx.x;
  if (id < 16384){                              // w1A (i and j)
    int m = id & 8191;
    int i = m & 7, lane = (m >> 3) & 63, kbmt = m >> 9;
    int kb = kbmt & 1, mt = kbmt >> 1;
    int row = lane & 15;
    int feat = 32 * (mt >> 1) + 8 * (row >> 2) + 4 * (mt & 1) + (row & 3);
    int k = kb * 32 + ((lane >> 4) & 3) * 8 + i;
    const float* w = (id < 8192) ? i1w : j1w;
    float v = w[k * 128 + feat];
    if (k < 2) v += w[(64 + k) * 128 + feat];   // fold hx dup-columns
    ((id < 8192) ? wi1A : wj1A)[m] = f2bf(v);
  } else if (id < 49152){                       // w2A (i and j)
    int m = (id - 16384) & 16383;
    int i = m & 7, lane = (m >> 3) & 63, unt = m >> 9;
    int u = unt & 3, nt = unt >> 2;
    int out  = nt * 16 + (lane & 15);
    int feat = u * 32 + ((lane >> 4) & 3) * 8 + i;
    const float* w = (id < 32768) ? i2w : j2w;
    ((id < 32768) ? wi2A : wj2A)[m] = f2bf(w[feat * 128 + out]);
  }
}

// 256-thread block = 4 independent waves, ONE 64-node tile (4 sets of 16) per
// wave, one tile per wave lifetime (short-lived blocks, dispatch-order
// locality -- the structure proven clean in R3). ZERO LDS.
// Weight fragments are indexed [tile-step][lane] only, so the same loads are
// shared across all 4 node-sets: 1.5 KB of weight VMEM per node (R1 level)
// with no LDS roundtrip and lane-contiguous 16B loads.
__global__ __launch_bounds__(256, 2) void fused_node_kernel(
    const float* __restrict__ nodes, const float* __restrict__ node_mask,
    const int* __restrict__ offs,
    const ushort_t* __restrict__ wi1A, const ushort_t* __restrict__ wj1A,
    const ushort_t* __restrict__ wi2A, const ushort_t* __restrict__ wj2A,
    const float* __restrict__ i1b, const float* __restrict__ i2b,
    const float* __restrict__ j1b, const float* __restrict__ j2b,
    float* __restrict__ pooled, int N, int B){

  const int tid  = threadIdx.x;
  const int lane = tid & 63;
  const int lm   = lane & 15;
  const int quad = (lane >> 4) & 3;
  const int wv   = tid >> 6;
  const int base = (blockIdx.x * 4 + wv) * 64;
  if (base >= N) return;

  // ---- graph range for this 64-node tile (seeded gallop search) ----
  const int wg0 = __builtin_amdgcn_readfirstlane(
                    find_graph_seeded(offs, B, base, N));
  const int wg1 = __builtin_amdgcn_readfirstlane(
                    find_graph_seeded(offs, B, imin(base + 63, N - 1), N));
  const bool caseA = (wg0 == wg1);

  // ---- per-lane node mask (node = base + s*16 + lm) ----
  float mkn[4];
  #pragma unroll
  for (int s = 0; s < 4; ++s){
    int node = base + s * 16 + lm;
    mkn[s] = (node < N) ? node_mask[node] : 0.0f;
  }

  // ---- split-tile per-lane graph ids (rare: ~13% of tiles) ----
  int gfs[4], gls[4], grn[4];
  if (!caseA){
    #pragma unroll
    for (int s = 0; s < 4; ++s){
      gfs[s] = __builtin_amdgcn_readfirstlane(
                 find_graph(offs, wg0, wg1, imin(base + s * 16, N - 1)));
      gls[s] = __builtin_amdgcn_readfirstlane(
                 find_graph(offs, wg0, wg1, imin(base + s * 16 + 15, N - 1)));
      grn[s] = find_graph(offs, gfs[s], gls[s], imin(base + s * 16 + lm, N - 1));
    }
  }

  // ---- node B-fragments: 4 sets x 2 k-tiles (32 VGPR) ----
  bf16x8 nb[4][2];
  #pragma unroll
  for (int s = 0; s < 4; ++s){
    const int node = imin(base + s * 16 + lm, N - 1);
    const float* p = nodes + (size_t)node * 64;
    #pragma unroll
    for (int kb = 0; kb < 2; ++kb){
      float4 q0 = *(const float4*)(p + kb * 32 + quad * 8);
      float4 q1 = *(const float4*)(p + kb * 32 + quad * 8 + 4);
      nb[s][kb] = pack8(q0, q1);
    }
  }

  const f32x4 z4 = {0.f, 0.f, 0.f, 0.f};
  bf16x8 HB[2][4][4];   // [branch][set][u] L2 B-fragments, 128 VGPR

  // ---- layer 1: C-layout out, activations in-register, assemble HB ----
  #pragma unroll
  for (int br = 0; br < 2; ++br){
    const ushort_t* w1 = br ? wj1A : wi1A;
    const float*    b1 = br ? j1b  : i1b;
    #pragma unroll
    for (int u = 0; u < 4; ++u){
      unsigned t0[4], t1[4];
      #pragma unroll
      for (int half = 0; half < 2; ++half){
        const int mt = u * 2 + half;
        bf16x8 a0 = *(const bf16x8*)(w1 + ((size_t)(mt * 2 + 0) * 64 + lane) * 8);
        bf16x8 a1 = *(const bf16x8*)(w1 + ((size_t)(mt * 2 + 1) * 64 + lane) * 8);
        float4 bv = *(const float4*)(b1 + u * 32 + quad * 8 + half * 4);
        #pragma unroll
        for (int s = 0; s < 4; ++s){
          f32x4 acc = z4;
          acc = __builtin_amdgcn_mfma_f32_16x16x32_bf16(a0, nb[s][0], acc, 0, 0, 0);
          acc = __builtin_amdgcn_mfma_f32_16x16x32_bf16(a1, nb[s][1], acc, 0, 0, 0);
          float v0 = acc[0] + bv.x, v1 = acc[1] + bv.y;
          float v2 = acc[2] + bv.z, v3 = acc[3] + bv.w;
          if (br == 0){
            v0 = tanh_fast(v0); v1 = tanh_fast(v1); v2 = tanh_fast(v2); v3 = tanh_fast(v3);
          } else {
            v0 = selu_fast(v0); v1 = selu_fast(v1); v2 = selu_fast(v2); v3 = selu_fast(v3);
          }
          unsigned p0 = pk2(v0, v1), p1 = pk2(v2, v3);
          if (half == 0){ t0[s] = p0; t1[s] = p1; }
          else {
            union { bf16x8 v; unsigned w[4]; } c;
            c.w[0] = t0[s]; c.w[1] = t1[s]; c.w[2] = p0; c.w[3] = p1;
            HB[br][s][u] = c.v;
          }
        }
      }
    }
  }

  // ---- layer 2 + gate + mask + pooled reduction ----
  #pragma unroll
  for (int nt = 0; nt < 8; ++nt){
    float4 c2i = *(const float4*)(i2b + nt * 16 + quad * 4);
    float4 c2j = *(const float4*)(j2b + nt * 16 + quad * 4);
    f32x4 ai[4] = {z4, z4, z4, z4}, aj[4] = {z4, z4, z4, z4};
    #pragma unroll
    for (int u = 0; u < 4; ++u){
      bf16x8 wai = *(const bf16x8*)(wi2A + ((size_t)(nt * 4 + u) * 64 + lane) * 8);
      bf16x8 waj = *(const bf16x8*)(wj2A + ((size_t)(nt * 4 + u) * 64 + lane) * 8);
      #pragma unroll
      for (int s = 0; s < 4; ++s){
        ai[s] = __builtin_amdgcn_mfma_f32_16x16x32_bf16(wai, HB[0][s][u], ai[s], 0, 0, 0);
        aj[s] = __builtin_amdgcn_mfma_f32_16x16x32_bf16(waj, HB[1][s][u], aj[s], 0, 0, 0);
      }
    }
    const float cbi[4] = {c2i.x, c2i.y, c2i.z, c2i.w};
    const float cbj[4] = {c2j.x, c2j.y, c2j.z, c2j.w};
    if (caseA){
      float accr[4] = {0.f, 0.f, 0.f, 0.f};
      #pragma unroll
      for (int s = 0; s < 4; ++s)
        #pragma unroll
        for (int r = 0; r < 4; ++r){
          float g = sigmoid_fast(ai[s][r] + cbi[r]);
          accr[r] += g * (aj[s][r] + cbj[r]) * mkn[s];
        }
      #pragma unroll
      for (int r = 0; r < 4; ++r){
        accr[r] += __shfl_xor(accr[r], 1);
        accr[r] += __shfl_xor(accr[r], 2);
        accr[r] += __shfl_xor(accr[r], 4);
        accr[r] += __shfl_xor(accr[r], 8);
      }
      if (lm == 0){
        #pragma unroll
        for (int r = 0; r < 4; ++r)
          atomicAdd(&pooled[wg0 * 128 + nt * 16 + quad * 4 + r], accr[r]);
      }
    } else {
      #pragma unroll
      for (int s = 0; s < 4; ++s){
        float vals[4];
        #pragma unroll
        for (int r = 0; r < 4; ++r){
          float g = sigmoid_fast(ai[s][r] + cbi[r]);
          vals[r] = g * (aj[s][r] + cbj[r]) * mkn[s];
        }
        for (int g = gfs[s]; g <= gls[s]; ++g){
          float tt[4];
          #pragma unroll
          for (int r = 0; r < 4; ++r) tt[r] = (grn[s] == g) ? vals[r] : 0.0f;
          #pragma unroll
          for (int r = 0; r < 4; ++r){
            tt[r] += __shfl_xor(tt[r], 1);
            tt[r] += __shfl_xor(tt[r], 2);
            tt[r] += __shfl_xor(tt[r], 4);
            tt[r] += __shfl_xor(tt[r], 8);
          }
          if (lm == 0){
            #pragma unroll
            for (int r = 0; r < 4; ++r)
              atomicAdd(&pooled[g * 128 + nt * 16 + quad * 4 + r], tt[r]);
          }
        }
      }
    }
  }
}

// head: out[g] = selu(pooled[g] @ h1_w + h1_b) @ h2_w + h2_b   (fp32)
__global__ __launch_bounds__(128) void head_kernel(
    const float* __restrict__ pooled, const float* __restrict__ h1w,
    const float* __restrict__ h1b, const float* __restrict__ h2w,
    const float* __restrict__ h2b, float* __restrict__ out){
  __shared__ float pg[128];
  __shared__ float red[64];
  const int g = blockIdx.x, t = threadIdx.x;
  pg[t] = pooled[g * 128 + t];
  __syncthreads();
  float acc = h1b[t];
  #pragma unroll 8
  for (int k = 0; k < 128; ++k) acc += pg[k] * h1w[k * 128 + t];
  float s = selu_fast(acc) * h2w[t];
  if (t >= 64) red[t - 64] = s;
  __syncthreads();
  if (t < 64){
    float v = s + red[t];
    #pragma unroll
    for (int o = 32; o > 0; o >>= 1) v += __shfl_down(v, o);
    if (t == 0) out[g] = v + h2b[0];
  }
}

extern "C" void kernel_launch(void* const* d_in, const int* in_sizes, int n_in,
                              void* d_out, int out_size, void* d_ws, size_t ws_size,
                              hipStream_t stream){
  const float* nodes     = (const float*)d_in[0];
  const float* node_mask = (const float*)d_in[1];
  const int*   n_node    = (const int*)  d_in[2];
  const float* i1w = (const float*)d_in[3];
  const float* i1b = (const float*)d_in[4];
  const float* i2w = (const float*)d_in[5];
  const float* i2b = (const float*)d_in[6];
  const float* j1w = (const float*)d_in[7];
  const float* j1b = (const float*)d_in[8];
  const float* j2w = (const float*)d_in[9];
  const float* j2b = (const float*)d_in[10];
  const float* h1w = (const float*)d_in[11];
  const float* h1b = (const float*)d_in[12];
  const float* h2w = (const float*)d_in[13];
  const float* h2b = (const float*)d_in[14];
  float* out = (float*)d_out;

  const int N = in_sizes[0] / 64;
  const int B = in_sizes[2];

  char* ws = (char*)d_ws;
  float* pooled = (float*)ws;                                    // B*128 f32
  size_t off = (size_t)B * 128 * 4;
  int* offs = (int*)(ws + off);                                  // B+1 ints
  off += (((size_t)(B + 1) * 4 + 255) & ~(size_t)255);
  ushort_t* wi1A = (ushort_t*)(ws + off);                        // 8192
  ushort_t* wj1A = wi1A + 8192;                                  // 8192
  ushort_t* wi2A = wj1A + 8192;                                  // 16384
  ushort_t* wj2A = wi2A + 16384;                                 // 16384

  int zblk = (B * 128 + 255) / 256;
  prep_kernel<<<193 + zblk, 256, 0, stream>>>(i1w, j1w, i2w, j2w, wi1A, wj1A, wi2A, wj2A,
                                              n_node, offs, pooled, B);

  int nblk = (N + 255) / 256;
  fused_node_kernel<<<nblk, 256, 0, stream>>>(nodes, node_mask, offs,
                                              wi1A, wj1A, wi2A, wj2A,
                                              i1b, i2b, j1b, j2b, pooled, N, B);
  head_kernel<<<B, 128, 0, stream>>>(pooled, h1w, h1b, h2w, h2b, out);
}

// Round 6
// 542.636 us; speedup vs baseline: 2.6805x; 1.0325x over previous
//
#include <hip/hip_runtime.h>
#include <hip/hip_bf16.h>

typedef __bf16 bf16x8 __attribute__((ext_vector_type(8)));
typedef float f32x4 __attribute__((ext_vector_type(4)));
typedef unsigned short ushort_t;

#define LOG2E      1.4426950408889634f
#define SELU_SCALE 1.0507009873554805f
#define SELU_ALPHA 1.6732632423543772f

__device__ __forceinline__ float fexp2(float x){ return __builtin_amdgcn_exp2f(x); }
__device__ __forceinline__ float frcp (float x){ return __builtin_amdgcn_rcpf(x); }
__device__ __forceinline__ float tanh_fast(float x){
  return 1.0f - 2.0f * frcp(fexp2(x * (2.0f * LOG2E)) + 1.0f);
}
__device__ __forceinline__ float sigmoid_fast(float x){
  return frcp(1.0f + fexp2(-LOG2E * x));
}
__device__ __forceinline__ float selu_fast(float x){
  float e = SELU_ALPHA * (fexp2(LOG2E * x) - 1.0f);
  return SELU_SCALE * (x > 0.0f ? x : e);
}
__device__ __forceinline__ unsigned short f2bf(float f){
  unsigned u = __builtin_bit_cast(unsigned, f);
  u += 0x7fffu + ((u >> 16) & 1u);          // RNE
  return (unsigned short)(u >> 16);
}
__device__ __forceinline__ unsigned pk2(float a, float b){
#if __has_builtin(__builtin_amdgcn_cvt_pk_bf16_f32)
  typedef __bf16 bf2 __attribute__((ext_vector_type(2)));
  union { bf2 v; unsigned u; } c;
  c.v = __builtin_amdgcn_cvt_pk_bf16_f32(a, b);
  return c.u;
#else
  unsigned ua = __builtin_bit_cast(unsigned, a);
  ua += 0x7fffu + ((ua >> 16) & 1u);
  unsigned ub = __builtin_bit_cast(unsigned, b);
  ub += 0x7fffu + ((ub >> 16) & 1u);
  return (ua >> 16) | (ub & 0xffff0000u);
#endif
}
__device__ __forceinline__ bf16x8 pack8(float4 a, float4 b){
  union { bf16x8 v; unsigned u[4]; } c;
  c.u[0] = pk2(a.x, a.y); c.u[1] = pk2(a.z, a.w);
  c.u[2] = pk2(b.x, b.y); c.u[3] = pk2(b.z, b.w);
  return c.v;
}
__device__ __forceinline__ int imin(int a, int b){ return a < b ? a : b; }
__device__ __forceinline__ int imax(int a, int b){ return a > b ? a : b; }

// largest g in [lo,hi] with offs[g] <= n  (binary; used for narrow split ranges)
__device__ __forceinline__ int find_graph(const int* __restrict__ offs, int lo, int hi, int n){
  while (lo < hi){
    int mid = (lo + hi + 1) >> 1;
    if (offs[mid] <= n) lo = mid; else hi = mid - 1;
  }
  return lo;
}

// seeded + gallop: graphs are near-uniform (~N/B nodes), so the estimate is
// off by <=1-2; ~2-3 dependent loads instead of 11 binary-search probes.
__device__ __forceinline__ int find_graph_seeded(const int* __restrict__ offs,
                                                 int B, int n, int N){
  int g = (int)(((long long)n * B) / N);
  g = imin(imax(g, 0), B - 1);
  while (g < B - 1 && offs[g + 1] <= n) ++g;
  while (g > 0 && offs[g] > n) --g;
  return g;
}

// Weight prep. Fragment-native layouts so every fused-kernel weight load is a
// lane-contiguous 16B load:
//   w1A[((mt*2+kb)*64 + lane)*8 + i] = W1fold[k = kb*32 + (lane>>4)*8 + i]
//                                           [feat = F(mt, lane&15)]
//   F(mt,row) = 32*(mt>>1) + 8*(row>>2) + 4*(mt&1) + (row&3)
//   (row-permutation makes the L1 C-tile pair (2u,2u+1) assemble into a
//    NATURAL-order 16x16x32 B-fragment for layer 2 -- no LDS transpose)
//   w2A[((nt*4+u)*64 + lane)*8 + i] = W2T[out = nt*16 + (lane&15)]
//                                        [feat = u*32 + (lane>>4)*8 + i]
// blocks 0..191: weights; block 192: prefix scan; blocks 193..: zero pooled
__global__ __launch_bounds__(256) void prep_kernel(
    const float* __restrict__ i1w, const float* __restrict__ j1w,
    const float* __restrict__ i2w, const float* __restrict__ j2w,
    ushort_t* __restrict__ wi1A, ushort_t* __restrict__ wj1A,
    ushort_t* __restrict__ wi2A, ushort_t* __restrict__ wj2A,
    const int* __restrict__ n_node, int* __restrict__ offs,
    float* __restrict__ pooled, int B){
  if (blockIdx.x >= 193){
    int id = (blockIdx.x - 193) * 256 + threadIdx.x;
    if (id < B * 128) pooled[id] = 0.0f;
    return;
  }
  if (blockIdx.x == 192){
    __shared__ int part[256];
    const int t = threadIdx.x;
    const int chunk = (B + 255) / 256;
    int s = 0;
    for (int i = 0; i < chunk; ++i){ int idx = t * chunk + i; if (idx < B) s += n_node[idx]; }
    part[t] = s;
    __syncthreads();
    if (t == 0){
      int run = 0;
      for (int i = 0; i < 256; ++i){ int v = part[i]; part[i] = run; run += v; }
      offs[B] = run;
    }
    __syncthreads();
    int run = part[t];
    for (int i = 0; i < chunk; ++i){
      int idx = t * chunk + i;
      if (idx < B){ offs[idx] = run; run += n_node[idx]; }
    }
    return;
  }
  int id = blockIdx.x * 256 + threadIdx.x;
  if (id < 16384){                              // w1A (i and j)
    int m = id & 8191;
    int i = m & 7, lane = (m >> 3) & 63, kbmt = m >> 9;
    int kb = kbmt & 1, mt = kbmt >> 1;
    int row = lane & 15;
    int feat = 32 * (mt >> 1) + 8 * (row >> 2) + 4 * (mt & 1) + (row & 3);
    int k = kb * 32 + ((lane >> 4) & 3) * 8 + i;
    const float* w = (id < 8192) ? i1w : j1w;
    float v = w[k * 128 + feat];
    if (k < 2) v += w[(64 + k) * 128 + feat];   // fold hx dup-columns
    ((id < 8192) ? wi1A : wj1A)[m] = f2bf(v);
  } else if (id < 49152){                       // w2A (i and j)
    int m = (id - 16384) & 16383;
    int i = m & 7, lane = (m >> 3) & 63, unt = m >> 9;
    int u = unt & 3, nt = unt >> 2;
    int out  = nt * 16 + (lane & 15);
    int feat = u * 32 + ((lane >> 4) & 3) * 8 + i;
    const float* w = (id < 32768) ? i2w : j2w;
    ((id < 32768) ? wi2A : wj2A)[m] = f2bf(w[feat * 128 + out]);
  }
}

// 512-thread block = 8 waves. Block cooperatively stages w2A (both branches,
// 64 KB) in LDS ONCE, one __syncthreads, then each wave processes ONE 32-node
// tile (the proven 64-VGPR R3 body) and exits. Rationale: w2A (64 KB) through
// the 32 KB L1 self-evicts every tile -> every wave's critical path was a
// queue of L2 round trips that more occupancy could NOT hide (R1/R3/R5 all
// pinned at ~32-40 us/wave). LDS-resident w2A has fixed short latency and no
// queue collapse; L1 is freed for w1A (32 KB, exactly fits) + node stream.
// No persistence / grid-stride (R4 failure), no aggressive min-waves clamp
// (R2/R4 failure). LDS 64 KB -> 2 blocks/CU = 16 waves/CU cap; VGPR ~64-80.
__global__ __launch_bounds__(512, 2) void fused_node_kernel(
    const float* __restrict__ nodes, const float* __restrict__ node_mask,
    const int* __restrict__ offs,
    const ushort_t* __restrict__ wi1A, const ushort_t* __restrict__ wj1A,
    const ushort_t* __restrict__ w2A,   // wi2A || wj2A, contiguous 64 KB
    const float* __restrict__ i1b, const float* __restrict__ i2b,
    const float* __restrict__ j1b, const float* __restrict__ j2b,
    float* __restrict__ pooled, int N, int B){

  __shared__ __align__(16) ushort_t W2s[32768];   // 64 KB: i at 0, j at +16384

  const int tid  = threadIdx.x;
  const int lane = tid & 63;
  const int lm   = lane & 15;
  const int quad = (lane >> 4) & 3;
  const int wv   = tid >> 6;

  // ---- one-time cooperative LDS fill (4096 x 16B), ALL waves participate ----
  #pragma unroll
  for (int c = 0; c < 8; ++c)
    ((uint4*)W2s)[tid + c * 512] = ((const uint4*)w2A)[tid + c * 512];
  __syncthreads();

  const int base = (blockIdx.x * 8 + wv) * 32;
  if (base >= N) return;

  // ---- graph range for this 32-node tile (seeded gallop search) ----
  const int wg0 = __builtin_amdgcn_readfirstlane(
                    find_graph_seeded(offs, B, base, N));
  const int wg1 = __builtin_amdgcn_readfirstlane(
                    find_graph_seeded(offs, B, imin(base + 31, N - 1), N));
  const bool caseA = (wg0 == wg1);

  // ---- per-lane node mask (node = base + s*16 + lm) ----
  float mkn[2];
  #pragma unroll
  for (int s = 0; s < 2; ++s){
    int node = base + s * 16 + lm;
    mkn[s] = (node < N) ? node_mask[node] : 0.0f;
  }

  // ---- split-tile per-lane graph ids (rare: ~6.5% of tiles) ----
  int gfs[2], gls[2], grn[2];
  if (!caseA){
    #pragma unroll
    for (int s = 0; s < 2; ++s){
      gfs[s] = __builtin_amdgcn_readfirstlane(
                 find_graph(offs, wg0, wg1, imin(base + s * 16, N - 1)));
      gls[s] = __builtin_amdgcn_readfirstlane(
                 find_graph(offs, wg0, wg1, imin(base + s * 16 + 15, N - 1)));
      grn[s] = find_graph(offs, gfs[s], gls[s], imin(base + s * 16 + lm, N - 1));
    }
  }

  // ---- node B-fragments: 2 sets x 2 k-tiles ----
  bf16x8 nb[2][2];
  #pragma unroll
  for (int s = 0; s < 2; ++s){
    const int node = imin(base + s * 16 + lm, N - 1);
    const float* p = nodes + (size_t)node * 64;
    #pragma unroll
    for (int kb = 0; kb < 2; ++kb){
      float4 q0 = *(const float4*)(p + kb * 32 + quad * 8);
      float4 q1 = *(const float4*)(p + kb * 32 + quad * 8 + 4);
      nb[s][kb] = pack8(q0, q1);
    }
  }

  const f32x4 z4 = {0.f, 0.f, 0.f, 0.f};
  bf16x8 HB[2][2][4];   // [branch][set][u] L2 B-fragments, 64 VGPR

  // ---- layer 1: C-layout out, activations in-register, assemble HB ----
  #pragma unroll
  for (int br = 0; br < 2; ++br){
    const ushort_t* w1 = br ? wj1A : wi1A;
    const float*    b1 = br ? j1b  : i1b;
    #pragma unroll
    for (int u = 0; u < 4; ++u){
      unsigned t0[2], t1[2];
      #pragma unroll
      for (int half = 0; half < 2; ++half){
        const int mt = u * 2 + half;
        bf16x8 a0 = *(const bf16x8*)(w1 + ((size_t)(mt * 2 + 0) * 64 + lane) * 8);
        bf16x8 a1 = *(const bf16x8*)(w1 + ((size_t)(mt * 2 + 1) * 64 + lane) * 8);
        float4 bv = *(const float4*)(b1 + u * 32 + quad * 8 + half * 4);
        #pragma unroll
        for (int s = 0; s < 2; ++s){
          f32x4 acc = z4;
          acc = __builtin_amdgcn_mfma_f32_16x16x32_bf16(a0, nb[s][0], acc, 0, 0, 0);
          acc = __builtin_amdgcn_mfma_f32_16x16x32_bf16(a1, nb[s][1], acc, 0, 0, 0);
          float v0 = acc[0] + bv.x, v1 = acc[1] + bv.y;
          float v2 = acc[2] + bv.z, v3 = acc[3] + bv.w;
          if (br == 0){
            v0 = tanh_fast(v0); v1 = tanh_fast(v1); v2 = tanh_fast(v2); v3 = tanh_fast(v3);
          } else {
            v0 = selu_fast(v0); v1 = selu_fast(v1); v2 = selu_fast(v2); v3 = selu_fast(v3);
          }
          unsigned p0 = pk2(v0, v1), p1 = pk2(v2, v3);
          if (half == 0){ t0[s] = p0; t1[s] = p1; }
          else {
            union { bf16x8 v; unsigned w[4]; } c;
            c.w[0] = t0[s]; c.w[1] = t1[s]; c.w[2] = p0; c.w[3] = p1;
            HB[br][s][u] = c.v;
          }
        }
      }
    }
  }

  // ---- layer 2 + gate + mask + pooled reduction (w2 from LDS) ----
  #pragma unroll
  for (int nt = 0; nt < 8; ++nt){
    float4 c2i = *(const float4*)(i2b + nt * 16 + quad * 4);
    float4 c2j = *(const float4*)(j2b + nt * 16 + quad * 4);
    f32x4 ai[2] = {z4, z4}, aj[2] = {z4, z4};
    #pragma unroll
    for (int u = 0; u < 4; ++u){
      bf16x8 wai = *(const bf16x8*)(W2s + ((nt * 4 + u) * 64 + lane) * 8);
      bf16x8 waj = *(const bf16x8*)(W2s + 16384 + ((nt * 4 + u) * 64 + lane) * 8);
      #pragma unroll
      for (int s = 0; s < 2; ++s){
        ai[s] = __builtin_amdgcn_mfma_f32_16x16x32_bf16(wai, HB[0][s][u], ai[s], 0, 0, 0);
        aj[s] = __builtin_amdgcn_mfma_f32_16x16x32_bf16(waj, HB[1][s][u], aj[s], 0, 0, 0);
      }
    }
    const float cbi[4] = {c2i.x, c2i.y, c2i.z, c2i.w};
    const float cbj[4] = {c2j.x, c2j.y, c2j.z, c2j.w};
    if (caseA){
      float accr[4] = {0.f, 0.f, 0.f, 0.f};
      #pragma unroll
      for (int s = 0; s < 2; ++s)
        #pragma unroll
        for (int r = 0; r < 4; ++r){
          float g = sigmoid_fast(ai[s][r] + cbi[r]);
          accr[r] += g * (aj[s][r] + cbj[r]) * mkn[s];
        }
      #pragma unroll
      for (int r = 0; r < 4; ++r){
        accr[r] += __shfl_xor(accr[r], 1);
        accr[r] += __shfl_xor(accr[r], 2);
        accr[r] += __shfl_xor(accr[r], 4);
        accr[r] += __shfl_xor(accr[r], 8);
      }
      if (lm == 0){
        #pragma unroll
        for (int r = 0; r < 4; ++r)
          atomicAdd(&pooled[wg0 * 128 + nt * 16 + quad * 4 + r], accr[r]);
      }
    } else {
      #pragma unroll
      for (int s = 0; s < 2; ++s){
        float vals[4];
        #pragma unroll
        for (int r = 0; r < 4; ++r){
          float g = sigmoid_fast(ai[s][r] + cbi[r]);
          vals[r] = g * (aj[s][r] + cbj[r]) * mkn[s];
        }
        for (int g = gfs[s]; g <= gls[s]; ++g){
          float tt[4];
          #pragma unroll
          for (int r = 0; r < 4; ++r) tt[r] = (grn[s] == g) ? vals[r] : 0.0f;
          #pragma unroll
          for (int r = 0; r < 4; ++r){
            tt[r] += __shfl_xor(tt[r], 1);
            tt[r] += __shfl_xor(tt[r], 2);
            tt[r] += __shfl_xor(tt[r], 4);
            tt[r] += __shfl_xor(tt[r], 8);
          }
          if (lm == 0){
            #pragma unroll
            for (int r = 0; r < 4; ++r)
              atomicAdd(&pooled[g * 128 + nt * 16 + quad * 4 + r], tt[r]);
          }
        }
      }
    }
  }
}

// head: out[g] = selu(pooled[g] @ h1_w + h1_b) @ h2_w + h2_b   (fp32)
__global__ __launch_bounds__(128) void head_kernel(
    const float* __restrict__ pooled, const float* __restrict__ h1w,
    const float* __restrict__ h1b, const float* __restrict__ h2w,
    const float* __restrict__ h2b, float* __restrict__ out){
  __shared__ float pg[128];
  __shared__ float red[64];
  const int g = blockIdx.x, t = threadIdx.x;
  pg[t] = pooled[g * 128 + t];
  __syncthreads();
  float acc = h1b[t];
  #pragma unroll 8
  for (int k = 0; k < 128; ++k) acc += pg[k] * h1w[k * 128 + t];
  float s = selu_fast(acc) * h2w[t];
  if (t >= 64) red[t - 64] = s;
  __syncthreads();
  if (t < 64){
    float v = s + red[t];
    #pragma unroll
    for (int o = 32; o > 0; o >>= 1) v += __shfl_down(v, o);
    if (t == 0) out[g] = v + h2b[0];
  }
}

extern "C" void kernel_launch(void* const* d_in, const int* in_sizes, int n_in,
                              void* d_out, int out_size, void* d_ws, size_t ws_size,
                              hipStream_t stream){
  const float* nodes     = (const float*)d_in[0];
  const float* node_mask = (const float*)d_in[1];
  const int*   n_node    = (const int*)  d_in[2];
  const float* i1w = (const float*)d_in[3];
  const float* i1b = (const float*)d_in[4];
  const float* i2w = (const float*)d_in[5];
  const float* i2b = (const float*)d_in[6];
  const float* j1w = (const float*)d_in[7];
  const float* j1b = (const float*)d_in[8];
  const float* j2w = (const float*)d_in[9];
  const float* j2b = (const float*)d_in[10];
  const float* h1w = (const float*)d_in[11];
  const float* h1b = (const float*)d_in[12];
  const float* h2w = (const float*)d_in[13];
  const float* h2b = (const float*)d_in[14];
  float* out = (float*)d_out;

  const int N = in_sizes[0] / 64;
  const int B = in_sizes[2];

  char* ws = (char*)d_ws;
  float* pooled = (float*)ws;                                    // B*128 f32
  size_t off = (size_t)B * 128 * 4;
  int* offs = (int*)(ws + off);                                  // B+1 ints
  off += (((size_t)(B + 1) * 4 + 255) & ~(size_t)255);
  ushort_t* wi1A = (ushort_t*)(ws + off);                        // 8192
  ushort_t* wj1A = wi1A + 8192;                                  // 8192
  ushort_t* wi2A = wj1A + 8192;                                  // 16384
  ushort_t* wj2A = wi2A + 16384;                                 // 16384 (contiguous with wi2A)

  int zblk = (B * 128 + 255) / 256;
  prep_kernel<<<193 + zblk, 256, 0, stream>>>(i1w, j1w, i2w, j2w, wi1A, wj1A, wi2A, wj2A,
                                              n_node, offs, pooled, B);

  int nblk = (N + 255) / 256;   // 8 waves x 32 nodes = 256 nodes per block
  fused_node_kernel<<<nblk, 512, 0, stream>>>(nodes, node_mask, offs,
                                              wi1A, wj1A, wi2A,
                                              i1b, i2b, j1b, j2b, pooled, N, B);
  head_kernel<<<B, 128, 0, stream>>>(pooled, h1w, h1b, h2w, h2b, out);
}